// Round 24
// baseline (207.121 us; speedup 1.0000x reference)
//
#include <hip/hip_runtime.h>
#include <math.h>

namespace {
constexpr int kT = 16;
constexpr int kH = 56;
constexpr int kW = 56;
constexpr int kCAll = 256;
constexpr int kPlane = kH * kW;      // 3136
constexpr int kPlane4 = kPlane / 4;  // 784
constexpr size_t kGateBytes = (size_t)256 * kPlane * sizeof(float);  // 3.2 MB
constexpr int kSpan = 192 * kPlane4;      // c>=64 f4 per frame = 294*512
constexpr int kFrame4 = kCAll * kPlane4;  // f4 per frame
constexpr int kSbPerFrame = kSpan / 512;  // 294
typedef float nt4 __attribute__((ext_vector_type(4)));
}

__device__ __forceinline__ float4 nt_load4(const float4* p) {
  nt4 v = __builtin_nontemporal_load(reinterpret_cast<const nt4*>(p));
  return make_float4(v.x, v.y, v.z, v.w);
}
__device__ __forceinline__ void nt_store4(const float4& a, float4* p) {
  nt4 v = {a.x, a.y, a.z, a.w};
  __builtin_nontemporal_store(v, reinterpret_cast<nt4*>(p));
}

// ---------------- conv block, QUARTER-stripe (14 rows) ----------------
// r21 structure + TRIPLE-buffered global prefetch (A/B/C): loads issue 2-3
// stages ahead so loaded-HBM latency (~1-2k cyc under copy contention) is
// covered by ~3 stages of compute, not 1 (the r21 stall mechanism).
__device__ __forceinline__ void conv_block(
    int bid, int tid, const float* __restrict__ x,
    const float* __restrict__ gamma, const float* __restrict__ beta,
    const float* __restrict__ mean, const float* __restrict__ var,
    const float* __restrict__ cw, const float* __restrict__ cb,
    float* __restrict__ gate, float4* smb) {
  const int qs = bid & 3;
  const int g = (bid >> 2) & 1;
  const int t = (bid >> 3) & 15;
  const int n = bid >> 7;
  const int h0 = qs * 14;
  const int wid = tid >> 6;
  const int lane = tid & 63;
  const int r = lane >> 1;             // active < 14
  const int h = lane & 1;
  const int wbase = wid * 272;         // 16 rows x 17 f4

  for (int i = lane; i < 272; i += 64)
    smb[wbase + i] = make_float4(0.f, 0.f, 0.f, 0.f);

  int rr_u[4], fb_u[4], go_u[4];
  bool val_u[4];
  #pragma unroll
  for (int u = 0; u < 4; ++u) {
    const int j = lane + u * 64;
    bool v = (j < 224);                // 16 rows x 14 data blocks
    int rr = 0, fb = 0, go = 0;
    if (v) {
      rr = j / 14;
      fb = j - rr * 14;
      const int gr = h0 + rr - 1;
      v = ((unsigned)gr < (unsigned)kH);
      if (v) go = gr * 14 + fb;
    }
    rr_u[u] = rr; fb_u[u] = fb; go_u[u] = go; val_u[u] = v;
  }

  float acc[28];
  #pragma unroll
  for (int p = 0; p < 28; ++p) acc[p] = 0.f;

  auto loadS = [&](int s, float4 (&pf)[4]) {
    const int il = s / 3;
    const int kd = s - il * 3;
    const int tt = t + kd - 1;
    const int ch = g * 32 + wid * 8 + il;
    if (tt >= 0 && tt < kT) {
      const float4* src4 =
          (const float4*)x + ((size_t)(n * kT + tt) * kCAll + ch) * kPlane4;
      #pragma unroll
      for (int u = 0; u < 4; ++u)
        pf[u] = val_u[u] ? src4[go_u[u]] : make_float4(0.f, 0.f, 0.f, 0.f);
    } else {
      #pragma unroll
      for (int u = 0; u < 4; ++u) pf[u] = make_float4(0.f, 0.f, 0.f, 0.f);
    }
  };

  auto stageS = [&](int s, const float4 (&pf)[4]) {
    const int il = s / 3;
    const int kd = s - il * 3;
    const int tt = t + kd - 1;
    if (tt < 0 || tt >= kT) return;
    const int ch = g * 32 + wid * 8 + il;
    const float sc = gamma[ch] * rsqrtf(var[ch] + 1e-5f);
    const float sh = beta[ch] - mean[ch] * sc;
    #pragma unroll
    for (int u = 0; u < 4; ++u) {
      if (val_u[u]) {
        float4 a = pf[u];
        a.x = fmaxf(0.f, fmaf(a.x, sc, sh));
        a.y = fmaxf(0.f, fmaf(a.y, sc, sh));
        a.z = fmaxf(0.f, fmaf(a.z, sc, sh));
        a.w = fmaxf(0.f, fmaf(a.w, sc, sh));
        smb[wbase + rr_u[u] * 17 + fb_u[u] + 1] = a;
      }
    }
  };

  auto computeS = [&](int s) {
    const int il = s / 3;
    const int kd = s - il * 3;
    const int tt = t + kd - 1;
    if (tt < 0 || tt >= kT) return;
    if (r >= 14) return;
    const int ch = g * 32 + wid * 8 + il;
    const float* wbp = cw + ch * 27 + kd * 9;
    float wk[9];
    #pragma unroll
    for (int j = 0; j < 9; ++j) wk[j] = wbp[j];
    #pragma unroll
    for (int kh = 0; kh < 3; ++kh) {
      const int base = wbase + (r + kh) * 17 + 7 * h;
      float f[36];
      #pragma unroll
      for (int jj = 0; jj < 9; ++jj) {
        const float4 B = smb[base + jj];
        f[4 * jj + 0] = B.x; f[4 * jj + 1] = B.y;
        f[4 * jj + 2] = B.z; f[4 * jj + 3] = B.w;
      }
      const float w0 = wk[kh * 3 + 0];
      const float w1 = wk[kh * 3 + 1];
      const float w2 = wk[kh * 3 + 2];
      #pragma unroll
      for (int p = 0; p < 28; ++p)
        acc[p] = fmaf(f[p + 3], w0,
                 fmaf(f[p + 4], w1, fmaf(f[p + 5], w2, acc[p])));
    }
  };

  // Triple-buffered pipeline over 24 slices (loads issue 2-3 stages ahead).
  float4 A[4], B[4], C[4];
  loadS(0, A);
  loadS(1, B);
  for (int s = 0; s < 24; s += 3) {
    loadS(s + 2, C);                       // s+2 <= 23 always (24 % 3 == 0)
    stageS(s, A);
    computeS(s);
    if (s + 3 < 24) loadS(s + 3, A);
    stageS(s + 1, B);
    computeS(s + 1);
    if (s + 4 < 24) loadS(s + 4, B);
    stageS(s + 2, C);
    computeS(s + 2);
  }

  // Cross-wave reduction over 14x56=784 px (reuse smb as [4][784] floats).
  __syncthreads();
  float* smf = (float*)smb;
  if (r < 14) {
    const int q0 = r * 56 + h * 28;
    #pragma unroll
    for (int p = 0; p < 28; ++p) smf[wid * 784 + q0 + p] = acc[p];
  }
  __syncthreads();
  const float bias = cb[g];
  float* gp = gate + ((size_t)(n * 2 + g) * kT + t) * kPlane + h0 * kW;
  for (int q = tid; q < 784; q += 256) {
    float s = smf[q] + smf[784 + q] + smf[2 * 784 + q] + smf[3 * 784 + q];
    gp[q] = tanhf(s + bias);
  }
}

// Static NT copy of c>=64: wave-contiguous 8 KB superblocks (r17/r19 proven).
__device__ __forceinline__ void copy_engine_static(
    int engine, int nengines, int tid, const float4* __restrict__ x4,
    float4* __restrict__ o4, int nf, int skip_hole) {
  const int wave = engine * 4 + (tid >> 6);
  const int lane = tid & 63;
  const int nwaves = nengines * 4;
  const size_t nsb = (size_t)nf * kSbPerFrame;
  for (size_t sb = wave; sb < nsb; sb += nwaves) {
    const size_t base = sb * 512 + lane;
    const int f = (int)(base / kSpan);
    const int within = (int)(base - (size_t)f * kSpan);
    const size_t gbase = (size_t)f * kFrame4 + 64 * kPlane4 + within;
    float4 v[8];
    #pragma unroll
    for (int u = 0; u < 8; ++u) v[u] = nt_load4(&x4[gbase + u * 64]);
    if (!skip_hole || f != 126) {
      #pragma unroll
      for (int u = 0; u < 8; ++u) nt_store4(v[u], &o4[gbase + u * 64]);
    } else {
      #pragma unroll
      for (int u = 0; u < 8; ++u)
        if (within + u * 64 >= 3 * kPlane4) nt_store4(v[u], &o4[gbase + u * 64]);
    }
  }
}

// ---------------- fused conv + copy: 1536 blocks, 1 copy : 2 conv ----------------
__global__ __launch_bounds__(256, 2)
void fused_conv_copy_kernel(const float* __restrict__ x,
                            const float* __restrict__ gamma,
                            const float* __restrict__ beta,
                            const float* __restrict__ mean,
                            const float* __restrict__ var,
                            const float* __restrict__ cw,
                            const float* __restrict__ cb,
                            float* __restrict__ gate,
                            const float4* __restrict__ x4,
                            float4* __restrict__ o4,
                            int nf_copy, int skip_hole) {
  __shared__ float4 smb[4 * 272];      // 17.4 KB
  const int bid = blockIdx.x;          // 0..1535
  if (bid % 3 == 0) {
    copy_engine_static(bid / 3, 512, threadIdx.x, x4, o4, nf_copy, skip_hole);
    return;
  }
  const int cid = bid - bid / 3 - 1;   // 0..1023
  conv_block(cid, threadIdx.x, x, gamma, beta, mean, var, cw, cb, gate, smb);
}

// Column-wise gated shift (ws-mode only), NT x-loads / output-stores.
__global__ __launch_bounds__(256)
void shift_columns_kernel(const float4* __restrict__ x4,
                          const float4* __restrict__ g4,
                          float4* __restrict__ o4) {
  const int q = blockIdx.x * 256 + threadIdx.x;   // 0..401407
  const size_t xstep = (size_t)kFrame4;
  const int p = q % kPlane4;
  const int rem = q / kPlane4;
  const int m = rem & 31;
  const int half = (rem >> 5) & 1;
  const int n = rem >> 6;
  const int src_ch = half * 32 + m;
  const int k = 2 * (m & 15) + (m >> 4);
  const int c = half * 32 + k;
  const float4* xp = x4 + ((size_t)(n * kT) * kCAll + src_ch) * kPlane4 + p;
  const float4* gp = g4 + (size_t)((n * 2 + half) * kT) * kPlane4 + p;
  float4* op = o4 + ((size_t)(n * kT) * kCAll + c) * kPlane4 + p;
  if (half == 0) {     // left: out[t] = g[t+1]x[t+1] + x[t] - g[t]x[t]
    float4 xc = nt_load4(&xp[0]);
    float4 gc = gp[0];
    #pragma unroll
    for (int t = 0; t < kT; ++t) {
      float4 xn = make_float4(0.f, 0.f, 0.f, 0.f);
      float4 gn = make_float4(0.f, 0.f, 0.f, 0.f);
      if (t < kT - 1) {
        xn = nt_load4(&xp[(size_t)(t + 1) * xstep]);
        gn = gp[(t + 1) * kPlane4];
      }
      float4 res;
      res.x = gn.x * xn.x + xc.x - gc.x * xc.x;
      res.y = gn.y * xn.y + xc.y - gc.y * xc.y;
      res.z = gn.z * xn.z + xc.z - gc.z * xc.z;
      res.w = gn.w * xn.w + xc.w - gc.w * xc.w;
      nt_store4(res, &op[(size_t)t * xstep]);
      xc = xn; gc = gn;
    }
  } else {             // right: out[t] = g[t-1]x[t-1] + x[t] - g[t]x[t]
    float4 xprev = make_float4(0.f, 0.f, 0.f, 0.f);
    float4 gprev = make_float4(0.f, 0.f, 0.f, 0.f);
    #pragma unroll
    for (int t = 0; t < kT; ++t) {
      const float4 xc = nt_load4(&xp[(size_t)t * xstep]);
      const float4 gc = gp[t * kPlane4];
      float4 res;
      res.x = gprev.x * xprev.x + xc.x - gc.x * xc.x;
      res.y = gprev.y * xprev.y + xc.y - gc.y * xc.y;
      res.z = gprev.z * xprev.z + xc.z - gc.z * xc.z;
      res.w = gprev.w * xprev.w + xc.w - gc.w * xc.w;
      nt_store4(res, &op[(size_t)t * xstep]);
      xprev = xc; gprev = gc;
    }
  }
}

// ---------------- hole-mode fallback kernels (r13, proven) ----------------
__global__ __launch_bounds__(256)
void copy_gate_slice_kernel(float4* __restrict__ o4) {
  const int j = blockIdx.x * 256 + threadIdx.x;
  if (j >= 3 * kPlane4) return;
  const int q = j / kPlane4;
  const int rr = j - q * kPlane4;
  const int pidx = (q == 0) ? 239 : (q == 1 ? 254 : 255);
  const size_t G1 = (size_t)127 * kCAll * kPlane4;
  const size_t H = ((size_t)126 * kCAll + 64) * kPlane4;
  o4[H + j] = o4[G1 + (size_t)pidx * kPlane4 + rr];
}

__global__ __launch_bounds__(256)
void shift_c64_kernel(const float4* __restrict__ x4,
                      const float4* __restrict__ g4,
                      float4* __restrict__ o4, int nf) {
  const size_t total = (size_t)nf * 64 * kPlane4;
  const size_t j = (size_t)blockIdx.x * 256 + threadIdx.x;
  if (j >= total) return;
  const int p = (int)(j % kPlane4);
  const size_t rest = j / kPlane4;
  const int c = (int)(rest % 64);
  const int f = (int)(rest / 64);
  const int n = f >> 4;
  const int t = f & 15;
  const int half = c >> 5;
  const int k = c & 31;
  const int m = ((k & 1) << 4) + (k >> 1);
  const int src_ch = half * 32 + m;
  const size_t xcur = ((size_t)f * kCAll + src_ch) * kPlane4 + p;
  const size_t gbase = (size_t)(n * 2 + half) * kT * kPlane4 + p;
  const float4 xc = x4[xcur];
  const float4 gc = g4[gbase + (size_t)t * kPlane4];
  float4 y = make_float4(0.f, 0.f, 0.f, 0.f);
  if (half == 0) {
    if (t < kT - 1) {
      const float4 xn = x4[xcur + (size_t)kCAll * kPlane4];
      const float4 gn = g4[gbase + (size_t)(t + 1) * kPlane4];
      y.x = gn.x * xn.x; y.y = gn.y * xn.y; y.z = gn.z * xn.z; y.w = gn.w * xn.w;
    }
  } else {
    if (t > 0) {
      const float4 xp = x4[xcur - (size_t)kCAll * kPlane4];
      const float4 gp = g4[gbase + (size_t)(t - 1) * kPlane4];
      y.x = gp.x * xp.x; y.y = gp.y * xp.y; y.z = gp.z * xp.z; y.w = gp.w * xp.w;
    }
  }
  const size_t oidx = ((size_t)f * kCAll + c) * kPlane4 + p;
  float4 res;
  res.x = y.x + (xc.x - gc.x * xc.x);
  res.y = y.y + (xc.y - gc.y * xc.y);
  res.z = y.z + (xc.z - gc.z * xc.z);
  res.w = y.w + (xc.w - gc.w * xc.w);
  o4[oidx] = res;
}

__global__ __launch_bounds__(256)
void last_frame_kernel(const float4* __restrict__ x4, float4* o4) {
  const int idx = blockIdx.x * 256 + threadIdx.x;
  if (idx >= kCAll * kPlane4) return;
  const size_t F127 = (size_t)127 * kCAll * kPlane4;
  const int p = idx % kPlane4;
  const int c = idx / kPlane4;
  if (c >= 64) { o4[F127 + idx] = x4[F127 + idx]; return; }
  const size_t H = ((size_t)126 * kCAll + 64) * kPlane4;
  const int half = c >> 5;
  const int k = c & 31;
  const int m = ((k & 1) << 4) + (k >> 1);
  const int src_ch = half * 32 + m;
  const float4 xc = x4[F127 + (size_t)src_ch * kPlane4 + p];
  float4 gc;
  float4 y = make_float4(0.f, 0.f, 0.f, 0.f);
  if (half == 0) {
    gc = o4[H + 0 * kPlane4 + p];
  } else {
    gc = o4[H + 2 * kPlane4 + p];
    const float4 gp = o4[H + 1 * kPlane4 + p];
    const float4 xp = x4[((size_t)126 * kCAll + src_ch) * kPlane4 + p];
    y.x = gp.x * xp.x; y.y = gp.y * xp.y; y.z = gp.z * xp.z; y.w = gp.w * xp.w;
  }
  float4 res;
  res.x = y.x + (xc.x - gc.x * xc.x);
  res.y = y.y + (xc.y - gc.y * xc.y);
  res.z = y.z + (xc.z - gc.z * xc.z);
  res.w = y.w + (xc.w - gc.w * xc.w);
  o4[F127 + idx] = res;
}

__global__ __launch_bounds__(256)
void fix_hole_kernel(const float4* __restrict__ x4, float4* __restrict__ o4) {
  const int j = blockIdx.x * 256 + threadIdx.x;
  if (j >= 3 * kPlane4) return;
  const size_t H = ((size_t)126 * kCAll + 64) * kPlane4;
  o4[H + j] = x4[H + j];
}

extern "C" void kernel_launch(void* const* d_in, const int* in_sizes, int n_in,
                              void* d_out, int out_size, void* d_ws, size_t ws_size,
                              hipStream_t stream) {
  const float* x     = (const float*)d_in[0];
  const float* gamma = (const float*)d_in[1];
  const float* beta  = (const float*)d_in[2];
  const float* mean  = (const float*)d_in[3];
  const float* var   = (const float*)d_in[4];
  const float* cw    = (const float*)d_in[5];
  const float* cb    = (const float*)d_in[6];
  float* out = (float*)d_out;
  const float4* x4v = (const float4*)x;
  float4* o4v = (float4*)out;

  const bool have_ws = (d_ws != nullptr) && (ws_size >= kGateBytes);
  float* gate = have_ws ? (float*)d_ws : out + (size_t)127 * kCAll * kPlane;
  const int nf = have_ws ? 128 : 127;
  const int skip_hole = have_ws ? 0 : 1;

  // Phase 1: 1536 persistent blocks — 512 NT-copy engines + 1024 conv blocks.
  fused_conv_copy_kernel<<<1536, 256, 0, stream>>>(
      x, gamma, beta, mean, var, cw, cb, gate, x4v, o4v, nf, skip_hole);

  if (have_ws) {
    shift_columns_kernel<<<1568, 256, 0, stream>>>(
        x4v, (const float4*)gate, o4v);
  } else {
    copy_gate_slice_kernel<<<10, 256, 0, stream>>>(o4v);
    const int shift_total = nf * 64 * kPlane4;
    shift_c64_kernel<<<(shift_total + 255) / 256, 256, 0, stream>>>(
        x4v, (const float4*)gate, o4v, nf);
    last_frame_kernel<<<(kCAll * kPlane4 + 255) / 256, 256, 0, stream>>>(x4v, o4v);
    fix_hole_kernel<<<10, 256, 0, stream>>>(x4v, o4v);
  }
}

// Round 25
// 195.879 us; speedup vs baseline: 1.0574x; 1.0574x over previous
//
#include <hip/hip_runtime.h>
#include <math.h>

namespace {
constexpr int kT = 16;
constexpr int kH = 56;
constexpr int kW = 56;
constexpr int kCAll = 256;
constexpr int kPlane = kH * kW;      // 3136
constexpr int kPlane4 = kPlane / 4;  // 784
constexpr size_t kGateBytes = (size_t)256 * kPlane * sizeof(float);  // 3.2 MB
constexpr int kSpan = 192 * kPlane4;      // c>=64 f4 per frame = 294*512
constexpr int kFrame4 = kCAll * kPlane4;  // f4 per frame
constexpr int kSbPerFrame = kSpan / 512;  // 294
typedef float nt4 __attribute__((ext_vector_type(4)));
}

__device__ __forceinline__ float4 nt_load4(const float4* p) {
  nt4 v = __builtin_nontemporal_load(reinterpret_cast<const nt4*>(p));
  return make_float4(v.x, v.y, v.z, v.w);
}
__device__ __forceinline__ void nt_store4(const float4& a, float4* p) {
  nt4 v = {a.x, a.y, a.z, a.w};
  __builtin_nontemporal_store(v, reinterpret_cast<nt4*>(p));
}

// ---------------- conv block, QUARTER-stripe (14 rows) ----------------
// bid in [0,1024) = (((n*16+t)*2+g)*4 + qs). Wave w owns ic w*8..w*8+7
// (24 slices, reg double-buffered). LDS per wave: 16 rows x 17 f4 (odd
// stride -> conflict-free), rows h0-1..h0+14, data slots 1..14, halo 0.
// Staging: 224 items/slice, 4/lane, all 64 lanes. Compute: 28 active lanes
// (r=lane>>1<14, h=lane&1), 28 cols each. 4-wave LDS reduce + tanh fused.
__device__ __forceinline__ void conv_block(
    int bid, int tid, const float* __restrict__ x,
    const float* __restrict__ gamma, const float* __restrict__ beta,
    const float* __restrict__ mean, const float* __restrict__ var,
    const float* __restrict__ cw, const float* __restrict__ cb,
    float* __restrict__ gate, float4* smb) {
  const int qs = bid & 3;
  const int g = (bid >> 2) & 1;
  const int t = (bid >> 3) & 15;
  const int n = bid >> 7;
  const int h0 = qs * 14;
  const int wid = tid >> 6;
  const int lane = tid & 63;
  const int r = lane >> 1;             // active < 14
  const int h = lane & 1;
  const int wbase = wid * 272;         // 16 rows x 17 f4

  for (int i = lane; i < 272; i += 64)
    smb[wbase + i] = make_float4(0.f, 0.f, 0.f, 0.f);

  int rr_u[4], fb_u[4], go_u[4];
  bool val_u[4];
  #pragma unroll
  for (int u = 0; u < 4; ++u) {
    const int j = lane + u * 64;
    bool v = (j < 224);                // 16 rows x 14 data blocks
    int rr = 0, fb = 0, go = 0;
    if (v) {
      rr = j / 14;
      fb = j - rr * 14;
      const int gr = h0 + rr - 1;
      v = ((unsigned)gr < (unsigned)kH);
      if (v) go = gr * 14 + fb;
    }
    rr_u[u] = rr; fb_u[u] = fb; go_u[u] = go; val_u[u] = v;
  }

  float acc[28];
  #pragma unroll
  for (int p = 0; p < 28; ++p) acc[p] = 0.f;

  auto loadS = [&](int s, float4 (&pf)[4]) {
    const int il = s / 3;
    const int kd = s - il * 3;
    const int tt = t + kd - 1;
    const int ch = g * 32 + wid * 8 + il;
    if (tt >= 0 && tt < kT) {
      const float4* src4 =
          (const float4*)x + ((size_t)(n * kT + tt) * kCAll + ch) * kPlane4;
      #pragma unroll
      for (int u = 0; u < 4; ++u)
        pf[u] = val_u[u] ? src4[go_u[u]] : make_float4(0.f, 0.f, 0.f, 0.f);
    } else {
      #pragma unroll
      for (int u = 0; u < 4; ++u) pf[u] = make_float4(0.f, 0.f, 0.f, 0.f);
    }
  };

  auto stageS = [&](int s, const float4 (&pf)[4]) {
    const int il = s / 3;
    const int kd = s - il * 3;
    const int tt = t + kd - 1;
    if (tt < 0 || tt >= kT) return;
    const int ch = g * 32 + wid * 8 + il;
    const float sc = gamma[ch] * rsqrtf(var[ch] + 1e-5f);
    const float sh = beta[ch] - mean[ch] * sc;
    #pragma unroll
    for (int u = 0; u < 4; ++u) {
      if (val_u[u]) {
        float4 a = pf[u];
        a.x = fmaxf(0.f, fmaf(a.x, sc, sh));
        a.y = fmaxf(0.f, fmaf(a.y, sc, sh));
        a.z = fmaxf(0.f, fmaf(a.z, sc, sh));
        a.w = fmaxf(0.f, fmaf(a.w, sc, sh));
        smb[wbase + rr_u[u] * 17 + fb_u[u] + 1] = a;
      }
    }
  };

  auto computeS = [&](int s) {
    const int il = s / 3;
    const int kd = s - il * 3;
    const int tt = t + kd - 1;
    if (tt < 0 || tt >= kT) return;
    if (r >= 14) return;
    const int ch = g * 32 + wid * 8 + il;
    const float* wbp = cw + ch * 27 + kd * 9;
    float wk[9];
    #pragma unroll
    for (int j = 0; j < 9; ++j) wk[j] = wbp[j];
    #pragma unroll
    for (int kh = 0; kh < 3; ++kh) {
      const int base = wbase + (r + kh) * 17 + 7 * h;
      float f[36];
      #pragma unroll
      for (int jj = 0; jj < 9; ++jj) {
        const float4 B = smb[base + jj];
        f[4 * jj + 0] = B.x; f[4 * jj + 1] = B.y;
        f[4 * jj + 2] = B.z; f[4 * jj + 3] = B.w;
      }
      const float w0 = wk[kh * 3 + 0];
      const float w1 = wk[kh * 3 + 1];
      const float w2 = wk[kh * 3 + 2];
      #pragma unroll
      for (int p = 0; p < 28; ++p)
        acc[p] = fmaf(f[p + 3], w0,
                 fmaf(f[p + 4], w1, fmaf(f[p + 5], w2, acc[p])));
    }
  };

  float4 A[4], B[4];
  loadS(0, A);
  for (int s2 = 0; s2 < 24; s2 += 2) {
    if (s2 + 1 < 24) loadS(s2 + 1, B);
    stageS(s2, A);
    computeS(s2);
    if (s2 + 2 < 24) loadS(s2 + 2, A);
    if (s2 + 1 < 24) { stageS(s2 + 1, B); computeS(s2 + 1); }
  }

  // Cross-wave reduction over 14x56=784 px (reuse smb as [4][784] floats).
  __syncthreads();
  float* smf = (float*)smb;
  if (r < 14) {
    const int q0 = r * 56 + h * 28;
    #pragma unroll
    for (int p = 0; p < 28; ++p) smf[wid * 784 + q0 + p] = acc[p];
  }
  __syncthreads();
  const float bias = cb[g];
  float* gp = gate + ((size_t)(n * 2 + g) * kT + t) * kPlane + h0 * kW;
  for (int q = tid; q < 784; q += 256) {
    float s = smf[q] + smf[784 + q] + smf[2 * 784 + q] + smf[3 * 784 + q];
    gp[q] = tanhf(s + bias);
  }
}

// Static NT copy of c>=64: wave-contiguous 8 KB superblocks (r17/r19 proven).
__device__ __forceinline__ void copy_engine_static(
    int engine, int nengines, int tid, const float4* __restrict__ x4,
    float4* __restrict__ o4, int nf, int skip_hole) {
  const int wave = engine * 4 + (tid >> 6);
  const int lane = tid & 63;
  const int nwaves = nengines * 4;
  const size_t nsb = (size_t)nf * kSbPerFrame;
  for (size_t sb = wave; sb < nsb; sb += nwaves) {
    const size_t base = sb * 512 + lane;
    const int f = (int)(base / kSpan);
    const int within = (int)(base - (size_t)f * kSpan);
    const size_t gbase = (size_t)f * kFrame4 + 64 * kPlane4 + within;
    float4 v[8];
    #pragma unroll
    for (int u = 0; u < 8; ++u) v[u] = nt_load4(&x4[gbase + u * 64]);
    if (!skip_hole || f != 126) {
      #pragma unroll
      for (int u = 0; u < 8; ++u) nt_store4(v[u], &o4[gbase + u * 64]);
    } else {
      #pragma unroll
      for (int u = 0; u < 8; ++u)
        if (within + u * 64 >= 3 * kPlane4) nt_store4(v[u], &o4[gbase + u * 64]);
    }
  }
}

// ---------------- fused conv + copy: 1536 blocks, 1 copy : 2 conv ----------------
__global__ __launch_bounds__(256, 2)
void fused_conv_copy_kernel(const float* __restrict__ x,
                            const float* __restrict__ gamma,
                            const float* __restrict__ beta,
                            const float* __restrict__ mean,
                            const float* __restrict__ var,
                            const float* __restrict__ cw,
                            const float* __restrict__ cb,
                            float* __restrict__ gate,
                            const float4* __restrict__ x4,
                            float4* __restrict__ o4,
                            int nf_copy, int skip_hole) {
  __shared__ float4 smb[4 * 272];      // 17.4 KB
  const int bid = blockIdx.x;          // 0..1535
  if (bid % 3 == 0) {
    copy_engine_static(bid / 3, 512, threadIdx.x, x4, o4, nf_copy, skip_hole);
    return;
  }
  const int cid = bid - bid / 3 - 1;   // 0..1023
  conv_block(cid, threadIdx.x, x, gamma, beta, mean, var, cw, cb, gate, smb);
}

// Column-wise gated shift (ws-mode only), NT x-loads / output-stores.
__global__ __launch_bounds__(256)
void shift_columns_kernel(const float4* __restrict__ x4,
                          const float4* __restrict__ g4,
                          float4* __restrict__ o4) {
  const int q = blockIdx.x * 256 + threadIdx.x;   // 0..401407
  const size_t xstep = (size_t)kFrame4;
  const int p = q % kPlane4;
  const int rem = q / kPlane4;
  const int m = rem & 31;
  const int half = (rem >> 5) & 1;
  const int n = rem >> 6;
  const int src_ch = half * 32 + m;
  const int k = 2 * (m & 15) + (m >> 4);
  const int c = half * 32 + k;
  const float4* xp = x4 + ((size_t)(n * kT) * kCAll + src_ch) * kPlane4 + p;
  const float4* gp = g4 + (size_t)((n * 2 + half) * kT) * kPlane4 + p;
  float4* op = o4 + ((size_t)(n * kT) * kCAll + c) * kPlane4 + p;
  if (half == 0) {     // left: out[t] = g[t+1]x[t+1] + x[t] - g[t]x[t]
    float4 xc = nt_load4(&xp[0]);
    float4 gc = gp[0];
    #pragma unroll
    for (int t = 0; t < kT; ++t) {
      float4 xn = make_float4(0.f, 0.f, 0.f, 0.f);
      float4 gn = make_float4(0.f, 0.f, 0.f, 0.f);
      if (t < kT - 1) {
        xn = nt_load4(&xp[(size_t)(t + 1) * xstep]);
        gn = gp[(t + 1) * kPlane4];
      }
      float4 res;
      res.x = gn.x * xn.x + xc.x - gc.x * xc.x;
      res.y = gn.y * xn.y + xc.y - gc.y * xc.y;
      res.z = gn.z * xn.z + xc.z - gc.z * xc.z;
      res.w = gn.w * xn.w + xc.w - gc.w * xc.w;
      nt_store4(res, &op[(size_t)t * xstep]);
      xc = xn; gc = gn;
    }
  } else {             // right: out[t] = g[t-1]x[t-1] + x[t] - g[t]x[t]
    float4 xprev = make_float4(0.f, 0.f, 0.f, 0.f);
    float4 gprev = make_float4(0.f, 0.f, 0.f, 0.f);
    #pragma unroll
    for (int t = 0; t < kT; ++t) {
      const float4 xc = nt_load4(&xp[(size_t)t * xstep]);
      const float4 gc = gp[t * kPlane4];
      float4 res;
      res.x = gprev.x * xprev.x + xc.x - gc.x * xc.x;
      res.y = gprev.y * xprev.y + xc.y - gc.y * xc.y;
      res.z = gprev.z * xprev.z + xc.z - gc.z * xc.z;
      res.w = gprev.w * xprev.w + xc.w - gc.w * xc.w;
      nt_store4(res, &op[(size_t)t * xstep]);
      xprev = xc; gprev = gc;
    }
  }
}

// ---------------- hole-mode fallback kernels (r13, proven) ----------------
__global__ __launch_bounds__(256)
void copy_gate_slice_kernel(float4* __restrict__ o4) {
  const int j = blockIdx.x * 256 + threadIdx.x;
  if (j >= 3 * kPlane4) return;
  const int q = j / kPlane4;
  const int rr = j - q * kPlane4;
  const int pidx = (q == 0) ? 239 : (q == 1 ? 254 : 255);
  const size_t G1 = (size_t)127 * kCAll * kPlane4;
  const size_t H = ((size_t)126 * kCAll + 64) * kPlane4;
  o4[H + j] = o4[G1 + (size_t)pidx * kPlane4 + rr];
}

__global__ __launch_bounds__(256)
void shift_c64_kernel(const float4* __restrict__ x4,
                      const float4* __restrict__ g4,
                      float4* __restrict__ o4, int nf) {
  const size_t total = (size_t)nf * 64 * kPlane4;
  const size_t j = (size_t)blockIdx.x * 256 + threadIdx.x;
  if (j >= total) return;
  const int p = (int)(j % kPlane4);
  const size_t rest = j / kPlane4;
  const int c = (int)(rest % 64);
  const int f = (int)(rest / 64);
  const int n = f >> 4;
  const int t = f & 15;
  const int half = c >> 5;
  const int k = c & 31;
  const int m = ((k & 1) << 4) + (k >> 1);
  const int src_ch = half * 32 + m;
  const size_t xcur = ((size_t)f * kCAll + src_ch) * kPlane4 + p;
  const size_t gbase = (size_t)(n * 2 + half) * kT * kPlane4 + p;
  const float4 xc = x4[xcur];
  const float4 gc = g4[gbase + (size_t)t * kPlane4];
  float4 y = make_float4(0.f, 0.f, 0.f, 0.f);
  if (half == 0) {
    if (t < kT - 1) {
      const float4 xn = x4[xcur + (size_t)kCAll * kPlane4];
      const float4 gn = g4[gbase + (size_t)(t + 1) * kPlane4];
      y.x = gn.x * xn.x; y.y = gn.y * xn.y; y.z = gn.z * xn.z; y.w = gn.w * xn.w;
    }
  } else {
    if (t > 0) {
      const float4 xp = x4[xcur - (size_t)kCAll * kPlane4];
      const float4 gp = g4[gbase + (size_t)(t - 1) * kPlane4];
      y.x = gp.x * xp.x; y.y = gp.y * xp.y; y.z = gp.z * xp.z; y.w = gp.w * xp.w;
    }
  }
  const size_t oidx = ((size_t)f * kCAll + c) * kPlane4 + p;
  float4 res;
  res.x = y.x + (xc.x - gc.x * xc.x);
  res.y = y.y + (xc.y - gc.y * xc.y);
  res.z = y.z + (xc.z - gc.z * xc.z);
  res.w = y.w + (xc.w - gc.w * xc.w);
  o4[oidx] = res;
}

__global__ __launch_bounds__(256)
void last_frame_kernel(const float4* __restrict__ x4, float4* o4) {
  const int idx = blockIdx.x * 256 + threadIdx.x;
  if (idx >= kCAll * kPlane4) return;
  const size_t F127 = (size_t)127 * kCAll * kPlane4;
  const int p = idx % kPlane4;
  const int c = idx / kPlane4;
  if (c >= 64) { o4[F127 + idx] = x4[F127 + idx]; return; }
  const size_t H = ((size_t)126 * kCAll + 64) * kPlane4;
  const int half = c >> 5;
  const int k = c & 31;
  const int m = ((k & 1) << 4) + (k >> 1);
  const int src_ch = half * 32 + m;
  const float4 xc = x4[F127 + (size_t)src_ch * kPlane4 + p];
  float4 gc;
  float4 y = make_float4(0.f, 0.f, 0.f, 0.f);
  if (half == 0) {
    gc = o4[H + 0 * kPlane4 + p];
  } else {
    gc = o4[H + 2 * kPlane4 + p];
    const float4 gp = o4[H + 1 * kPlane4 + p];
    const float4 xp = x4[((size_t)126 * kCAll + src_ch) * kPlane4 + p];
    y.x = gp.x * xp.x; y.y = gp.y * xp.y; y.z = gp.z * xp.z; y.w = gp.w * xp.w;
  }
  float4 res;
  res.x = y.x + (xc.x - gc.x * xc.x);
  res.y = y.y + (xc.y - gc.y * xc.y);
  res.z = y.z + (xc.z - gc.z * xc.z);
  res.w = y.w + (xc.w - gc.w * xc.w);
  o4[F127 + idx] = res;
}

__global__ __launch_bounds__(256)
void fix_hole_kernel(const float4* __restrict__ x4, float4* __restrict__ o4) {
  const int j = blockIdx.x * 256 + threadIdx.x;
  if (j >= 3 * kPlane4) return;
  const size_t H = ((size_t)126 * kCAll + 64) * kPlane4;
  o4[H + j] = x4[H + j];
}

extern "C" void kernel_launch(void* const* d_in, const int* in_sizes, int n_in,
                              void* d_out, int out_size, void* d_ws, size_t ws_size,
                              hipStream_t stream) {
  const float* x     = (const float*)d_in[0];
  const float* gamma = (const float*)d_in[1];
  const float* beta  = (const float*)d_in[2];
  const float* mean  = (const float*)d_in[3];
  const float* var   = (const float*)d_in[4];
  const float* cw    = (const float*)d_in[5];
  const float* cb    = (const float*)d_in[6];
  float* out = (float*)d_out;
  const float4* x4v = (const float4*)x;
  float4* o4v = (float4*)out;

  const bool have_ws = (d_ws != nullptr) && (ws_size >= kGateBytes);
  float* gate = have_ws ? (float*)d_ws : out + (size_t)127 * kCAll * kPlane;
  const int nf = have_ws ? 128 : 127;
  const int skip_hole = have_ws ? 0 : 1;

  // Phase 1: 1536 persistent blocks — 512 NT-copy engines + 1024 conv blocks.
  fused_conv_copy_kernel<<<1536, 256, 0, stream>>>(
      x, gamma, beta, mean, var, cw, cb, gate, x4v, o4v, nf, skip_hole);

  if (have_ws) {
    shift_columns_kernel<<<1568, 256, 0, stream>>>(
        x4v, (const float4*)gate, o4v);
  } else {
    copy_gate_slice_kernel<<<10, 256, 0, stream>>>(o4v);
    const int shift_total = nf * 64 * kPlane4;
    shift_c64_kernel<<<(shift_total + 255) / 256, 256, 0, stream>>>(
        x4v, (const float4*)gate, o4v, nf);
    last_frame_kernel<<<(kCAll * kPlane4 + 255) / 256, 256, 0, stream>>>(x4v, o4v);
    fix_hole_kernel<<<10, 256, 0, stream>>>(x4v, o4v);
  }
}